// Round 6
// baseline (709.138 us; speedup 1.0000x reference)
//
#include <hip/hip_runtime.h>
#include <stdint.h>

#define TB     400
#define OUTROW 160000   // T * 2F
#define NTHR   1024
#define GRID   256      // (dir 2) x (seq 128), one block per sequence per direction

typedef _Float16 half2_t __attribute__((ext_vector_type(2)));

#if defined(__has_builtin)
#  if __has_builtin(__builtin_amdgcn_fdot2)
#    define HAVE_FDOT2 1
#  endif
#endif

__device__ __forceinline__ float sigf(float x){ return 1.0f/(1.0f+__expf(-x)); }
__device__ __forceinline__ float tanhf_(float x){ float e=__expf(2.0f*x); return 1.0f - 2.0f/(e+1.0f); }
__device__ __forceinline__ uint32_t pkh(float a, float b){
  half2_t h; h.x = (_Float16)a; h.y = (_Float16)b;
  return __builtin_bit_cast(uint32_t, h);
}
__device__ __forceinline__ float dot2f(uint32_t w, uint32_t x, float acc){
#ifdef HAVE_FDOT2
  return __builtin_amdgcn_fdot2(__builtin_bit_cast(half2_t, w),
                                __builtin_bit_cast(half2_t, x), acc, false);
#else
  half2_t a = __builtin_bit_cast(half2_t, w), b = __builtin_bit_cast(half2_t, x);
  return acc + (float)a.x*(float)b.x + (float)a.y*(float)b.y;
#endif
}

// K layout (gates): k' 0..99 = x rows, k' 100..299 = m rows, 300..303 pad.
// xp pair-slots: [0,50) x, [50,150) m, [150,152) pad (zeroed once).
// Gates role (tid<800): c = tid>>1 (column), gh = tid&1 (k-half, 76 pairs each).
// Proj: h k 0..99, pad to 112; h2 pair-slots [0,50) h, [50,56) pad (zeroed once).
// Proj role (tid<800): pc = tid>>2 (column), kq = tid&3 (k-quarter, 14 pairs each).

__global__ __launch_bounds__(NTHR, 4)
void lstm_v6(const float* __restrict__ z,
             const float* __restrict__ c0f, const float* __restrict__ m0f,
             const float* __restrict__ c0b, const float* __restrict__ m0b,
             const float* __restrict__ Wf, const float* __restrict__ bfv,
             const float* __restrict__ Pf,
             const float* __restrict__ Wb, const float* __restrict__ bbv,
             const float* __restrict__ Pb,
             float* __restrict__ out)
{
  __shared__ __align__(16) uint32_t xp[152];  // packed f16-pair activations [x | m | pad]
  __shared__ float               ga[400];     // ACTIVATED gates
  __shared__ __align__(16) uint32_t h2[56];   // packed f16-pair h [h | pad]

  const int tid = threadIdx.x;
  const int dir = blockIdx.x >> 7;       // 0 fwd, 1 bwd
  const int seq = blockIdx.x & 127;

  const float* W   = dir ? Wb  : Wf;
  const float* bv  = dir ? bbv : bfv;
  const float* P   = dir ? Pb  : Pf;
  const float* c0v = dir ? c0b : c0f;
  const float* m0v = dir ? m0b : m0f;

  // ---- gates weights: 19 uint4 regs = 76 k-pairs of column c ----
  const int c  = tid >> 1, gh = tid & 1;
  const int gate = c / 100;              // 0:i 1:j 2:f 3:o
  uint4 wg[19];
  float bc = 0.f;
  if (tid < 800) {
    #pragma unroll
    for (int j = 0; j < 19; ++j) {
      float f[8];
      #pragma unroll
      for (int e = 0; e < 8; ++e) {
        int kk = 8*(19*gh + j) + e;
        f[e] = (kk < 300) ? W[(size_t)kk*400 + c] : 0.f;
      }
      wg[j] = make_uint4(pkh(f[0],f[1]), pkh(f[2],f[3]), pkh(f[4],f[5]), pkh(f[6],f[7]));
    }
    if (gh == 0) bc = bv[c] + (gate == 2 ? 1.0f : 0.0f);  // bias + FORGET_BIAS folded
  }

  // ---- proj weights: 7 uint2 regs = 14 k-pairs of column pc ----
  const int pc = tid >> 2, kq = tid & 3;
  uint2 pg[7];
  if (tid < 800) {
    #pragma unroll
    for (int j = 0; j < 7; ++j) {
      float f[4];
      #pragma unroll
      for (int e = 0; e < 4; ++e) {
        int hk = 28*kq + 4*j + e;
        f[e] = (hk < 100) ? P[(size_t)hk*200 + pc] : 0.f;
      }
      pg[j] = make_uint2(pkh(f[0],f[1]), pkh(f[2],f[3]));
    }
  }

  // ---- cell threads (tid<100): state in register ----
  float cs = 0.f;
  if (tid < 100) cs = c0v[(size_t)seq*100 + tid];

  // ---- init xp (x(t0) + m0 + pads), h2 pads ----
  if (tid < 50) {
    const float* zz = z + (size_t)seq*40000 + (size_t)(dir ? TB-1 : 0)*100;
    xp[tid] = pkh(zz[2*tid], zz[2*tid+1]);
  } else if (tid >= 64 && tid < 164) {
    int j = tid - 64;
    const float* mm = m0v + (size_t)seq*200;
    xp[50 + j] = pkh(mm[2*j], mm[2*j+1]);
  } else if (tid >= 192 && tid < 194) {
    xp[150 + (tid - 192)] = 0u;
  } else if (tid >= 256 && tid < 262) {
    h2[50 + (tid - 256)] = 0u;
  }
  __syncthreads();

  for (int t = 0; t < TB; ++t) {
    const int tt = dir ? (TB-1-t) : t;

    // x(t+1) prefetch by threads 800..899 (idle during gates/cell)
    float xpre = 0.f;
    if (tid >= 800 && tid < 900 && t+1 < TB) {
      int ttn = dir ? (TB-2-t) : (t+1);
      xpre = z[(size_t)seq*40000 + (size_t)ttn*100 + (tid - 800)];
    }

    // (1) gates: half-K dot (19 quads, 4 accs), pair-reduce, fused activation
    if (tid < 800) {
      float a0 = 0.f, a1 = 0.f, a2 = 0.f, a3 = 0.f;
      #pragma unroll
      for (int j = 0; j < 19; ++j) {
        uint4 xv = *(const uint4*)(xp + 4*(19*gh + j));
        a0 = dot2f(wg[j].x, xv.x, a0);
        a1 = dot2f(wg[j].y, xv.y, a1);
        a2 = dot2f(wg[j].z, xv.z, a2);
        a3 = dot2f(wg[j].w, xv.w, a3);
      }
      float a = (a0 + a1) + (a2 + a3);
      float r = a + __shfl_xor(a, 1);                  // sum k-halves (adjacent lanes)
      if (gh == 0) {
        float af = r + bc;
        // unified activation: tanh(x) = 2*sigmoid(2x)-1 (branch-free-ish)
        float arg = (gate == 1) ? af + af : af;
        float v = sigf(arg);
        ga[c] = (gate == 1) ? 2.0f*v - 1.0f : v;
      }
    }
    __syncthreads();                                   // B: ga (activated) ready

    // (2) cell update + h pack (gate order i,j,f,o)
    if (tid < 100) {
      float cc = ga[200+tid]*cs + ga[tid]*ga[100+tid];
      cs = cc;
      float h = ga[300+tid]*tanhf_(cc);
      float hn = __shfl_xor(h, 1);
      if ((tid & 1) == 0) h2[tid >> 1] = pkh(h, hn);
    }
    __syncthreads();                                   // C: h2 ready

    // (3) projection: quarter-K dot (7 uint2, 4 accs), 4-lane reduce, out + m-pack
    if (tid < 800) {
      float p0 = 0.f, p1 = 0.f, p2 = 0.f, p3 = 0.f;
      #pragma unroll
      for (int j = 0; j < 7; ++j) {
        uint2 hv = *(const uint2*)(h2 + 14*kq + 2*j);
        if (j & 1) { p2 = dot2f(pg[j].x, hv.x, p2); p3 = dot2f(pg[j].y, hv.y, p3); }
        else       { p0 = dot2f(pg[j].x, hv.x, p0); p1 = dot2f(pg[j].y, hv.y, p1); }
      }
      float p = (p0 + p1) + (p2 + p3);
      float m = p + __shfl_xor(p, 1);
      m += __shfl_xor(m, 2);                           // full sum in all 4 lanes
      if (kq == 0) {
        __builtin_nontemporal_store(m, out + (size_t)seq*OUTROW + (size_t)tt*400 + dir*200 + pc);
        float mn = __shfl_xor(m, 4);                   // m(pc^1), kq=0 lanes
        if ((pc & 1) == 0) xp[50 + (pc >> 1)] = pkh(m, mn);
      }
    }
    // (4) pack x(t+1)
    if (tid >= 800 && tid < 900 && t+1 < TB) {
      float xn = __shfl_xor(xpre, 1);
      if (((tid - 800) & 1) == 0) xp[(tid - 800) >> 1] = pkh(xpre, xn);
    }
    __syncthreads();                                   // A: xp ready for next step
  }
}

extern "C" void kernel_launch(void* const* d_in, const int* in_sizes, int n_in,
                              void* d_out, int out_size, void* d_ws, size_t ws_size,
                              hipStream_t stream) {
  (void)in_sizes; (void)n_in; (void)out_size; (void)d_ws; (void)ws_size;
  lstm_v6<<<GRID, NTHR, 0, stream>>>((const float*)d_in[0],
      (const float*)d_in[1], (const float*)d_in[2],
      (const float*)d_in[3], (const float*)d_in[4],
      (const float*)d_in[5], (const float*)d_in[6], (const float*)d_in[7],
      (const float*)d_in[8], (const float*)d_in[9], (const float*)d_in[10],
      (float*)d_out);
}